// Round 7
// baseline (493.484 us; speedup 1.0000x reference)
//
#include <hip/hip_runtime.h>
#include <stdint.h>

typedef __bf16 bf16_t;
typedef bf16_t bf16x8 __attribute__((ext_vector_type(8)));
typedef float  f32x4  __attribute__((ext_vector_type(4)));
typedef float  f32x2v __attribute__((ext_vector_type(2)));

static constexpr uint32_t PRIME = 2654435761u;
static constexpr uint32_t HMASK = (1u << 17) - 1u;   // HASHMAP_SIZE - 1
static constexpr uint32_t TSIZE = 1u << 17;

// dense mini-grid geometry, levels 0..7 (scale_l = 16*1.5^l, W = ceil(scale)+1)
static constexpr int NDALL  = 136642;   // 17^2+25^2+37^2+55^2+82^2+123^2+184^2+275^2

// features stored as fp8-e4m3 pairs, pre-scaled by 2^13 (|f|<=1e-4 -> +-0.82).
// un-scale 2^-13 is folded into the layer-0 weight fragments.
static constexpr float FSCALE = 8192.0f;        // 2^13
static constexpr float WSCALE = 1.0f / 8192.0f; // 2^-13

__device__ __forceinline__ uint32_t fbits(float f) {
    union { float f; uint32_t u; } v; v.f = f; return v.u;
}
__device__ __forceinline__ float asfloat(uint32_t u) {
    union { uint32_t u; float f; } v; v.u = u; return v.f;
}

// ---- fp8 pair encode/decode (OCP e4m3fn). HW path on gfx950, manual fallback.
__device__ __forceinline__ uint32_t enc8(float v) {   // manual e4m3fn RNE
    const uint32_t s = (fbits(v) >> 24) & 0x80u;
    float m = fabsf(v) * 0x1p-120f;                   // map e4m3 grid onto fp32 bits
    uint32_t u = fbits(m);
    u += 0x7FFFFu + ((u >> 20) & 1u);                 // RNE at bit 20
    return s | ((u >> 20) & 0x7fu);
}
__device__ __forceinline__ uint32_t pack8(float a, float b) {
#if __has_builtin(__builtin_amdgcn_cvt_pk_fp8_f32)
    return (uint32_t)__builtin_amdgcn_cvt_pk_fp8_f32(a, b, 0, false) & 0xffffu;
#else
    return enc8(a) | (enc8(b) << 8);
#endif
}
// unpack the low 16-bit fp8-pair of a dword (word-select must be an immediate)
template <bool HI>
__device__ __forceinline__ float2 unpack8w(uint32_t u) {
#if __has_builtin(__builtin_amdgcn_cvt_pk_f32_fp8)
    f32x2v r = __builtin_amdgcn_cvt_pk_f32_fp8((int)u, HI);
    return make_float2(r.x, r.y);
#else
    const uint32_t w = HI ? (u >> 16) : (u & 0xffffu);
    const float f0 = asfloat(((w & 0x80u) << 24) | ((w & 0x7fu) << 20)) * 0x1p120f;
    const float f1 = asfloat(((w & 0x8000u) << 16) | ((w & 0x7f00u) << 12)) * 0x1p120f;
    return make_float2(f0, f1);
#endif
}

// ---- single fused prepass (unchanged from R4, HW-verified):
// blocks [0,512):  repack levels 8..15 of fp32 [T][L][F] -> fp8-pair ushorts,
//                  level-major [l-8][T] (2 MB), LDS-tiled transpose.
// blocks [512,..): dense mini-grids, levels 0..7 (267 KB, fp8-pair u16).
__global__ __launch_bounds__(256)
void prepass_all(const float2* __restrict__ src, uint16_t* __restrict__ tab8,
                 uint16_t* __restrict__ dense) {
    __shared__ uint16_t ldsT[8 * 257];      // [l8][t_local], +1 pad
    const int tid = threadIdx.x;
    if (blockIdx.x < 512) {
        const int t0 = blockIdx.x * 256;    // 512 blocks x 256 t-entries
#pragma unroll
        for (int k = 0; k < 8; ++k) {
            const int j = k * 256 + tid;    // (t_local, l8): l8 fastest
            const int tl = j >> 3, l8 = j & 7;
            const float2 f = src[((size_t)(t0 + tl) << 4) + 8 + l8];
            ldsT[l8 * 257 + tl] = (uint16_t)pack8(f.x * FSCALE, f.y * FSCALE);
        }
        __syncthreads();
#pragma unroll
        for (int k = 0; k < 8; ++k)
            tab8[((uint32_t)k << 17) + t0 + tid] = ldsT[k * 257 + tid];
    } else {
        const int i = (blockIdx.x - 512) * 256 + tid;
        if (i >= NDALL) return;
        int lvl, W, off;
        if      (i <   289) { lvl = 0; W =  17; off = 0;     }
        else if (i <   914) { lvl = 1; W =  25; off = 289;   }
        else if (i <  2283) { lvl = 2; W =  37; off = 914;   }
        else if (i <  5308) { lvl = 3; W =  55; off = 2283;  }
        else if (i < 12032) { lvl = 4; W =  82; off = 5308;  }
        else if (i < 27161) { lvl = 5; W = 123; off = 12032; }
        else if (i < 61017) { lvl = 6; W = 184; off = 27161; }
        else                { lvl = 7; W = 275; off = 61017; }
        const int li = i - off;
        const uint32_t iy = (uint32_t)(li / W), ix = (uint32_t)(li % W);
        const uint32_t h = (ix ^ (iy * PRIME)) & HMASK;
        const float2 f = src[h * 16 + lvl];
        dense[i] = (uint16_t)pack8(f.x * FSCALE, f.y * FSCALE);
    }
}

// R4 gather structure + OCCUPANCY ATTACK. Session law (R0..R5): dur tracks
// resident waves (occ 30%->130us, 21%->144, 20%->160); in-wave ILP always
// lost the waves it cost. So: get under the 64-VGPR bracket (waves/CU cap
// 16 -> 32, m69 granule law):
//  (1) Bw0+Bw1 weight fragments -> LDS (12 KB, identical per-lane fragment
//      across waves; [frag][lane] 16B/lane layout = conflict-free b128).
//  (2) drop ldsTab; q0 reads global dense (lv0-3 tables are 10.6 KB ->
//      L1-resident). q0/q1 merge into ONE branch: -16 mem instr/iter.
//  (3) per-t fused MFMA->transpose-write (accumulator live range 16->4).
//  (4) __launch_bounds__(256,8) forces VGPR<=64.
__global__ __launch_bounds__(256, 8)
void fused_hash_mlp(const float* __restrict__ xin,
                    const uint16_t* __restrict__ tab8,   // hashed lv8..15, fp8
                    const uint16_t* __restrict__ dense,  // dense lv0..7, fp8
                    const float* __restrict__ w0, const float* __restrict__ b0,
                    const float* __restrict__ w1, const float* __restrict__ b1,
                    const float* __restrict__ w2, const float* __restrict__ b2,
                    float* __restrict__ out,
                    int nGroups)
{
    __shared__ __align__(16) bf16_t lds[4 * 16 * 64];     // 8192 B transpose tiles
    __shared__ __align__(16) bf16_t wLds[12 * 64 * 8];    // 12288 B weight frags

    const int tid  = threadIdx.x;
    const int wib  = tid >> 6;      // 0..3
    const int lane = tid & 63;
    const int q    = lane >> 4;
    const int n16  = lane & 15;
    const int m7   = n16 & 7;
    const int mb   = n16 >> 3;

    bf16_t* myLds = &lds[wib * (16 * 64)];

    // ---- stage weight B-fragments into LDS (once). Same fragment layout as
    // the register version; every wave reads the same data (lane-indexed).
    // slot 0..3  = Bw0[t]   (w0, absorbs 2^-13 un-scale)
    // slot 4..11 = Bw1[c*4+t]
    {
        bf16x8 tmp;
#pragma unroll
        for (int t = 0; t < 4; ++t) {
#pragma unroll
            for (int j = 0; j < 8; ++j)
                tmp[j] = (bf16_t)(w0[(q * 8 + j) * 64 + t * 16 + n16] * WSCALE);
            if (wib == 0) *(bf16x8*)&wLds[(t * 64 + lane) * 8] = tmp;
        }
#pragma unroll
        for (int c = 0; c < 2; ++c)
#pragma unroll
            for (int t = 0; t < 4; ++t) {
#pragma unroll
                for (int j = 0; j < 8; ++j)
                    tmp[j] = (bf16_t)w1[(c * 32 + q * 8 + j) * 64 + t * 16 + n16];
                if (wib == 0) *(bf16x8*)&wLds[((4 + c * 4 + t) * 64 + lane) * 8] = tmp;
            }
    }

    // small persistent register state: Bw2 (8), biases (9)
    bf16x8 Bw2[2];
#pragma unroll
    for (int c = 0; c < 2; ++c)
#pragma unroll
        for (int j = 0; j < 8; ++j)
            Bw2[c][j] = (n16 < 3) ? (bf16_t)w2[(c * 32 + q * 8 + j) * 3 + n16]
                                  : (bf16_t)0.0f;
    float bv0[4], bv1[4];
#pragma unroll
    for (int t = 0; t < 4; ++t) {
        bv0[t] = b0[t * 16 + n16];
        bv1[t] = b1[t * 16 + n16];
    }
    const float bv2 = (n16 < 3) ? b2[n16] : 0.0f;

    // scales for levels 4q..4q+3: 16*1.5^l = 3^l * 2^(4-l) is EXACT in fp32,
    // so pos/floor/hash bit-match the fp32 numpy reference.
    const float sb = 16.0f * ((q == 0) ? 1.0f :
                              (q == 1) ? 5.0625f :           // 1.5^4
                              (q == 2) ? 25.62890625f :      // 1.5^8
                                         129.746337890625f); // 1.5^12
    const float sc[4] = { sb, sb * 1.5f, sb * 2.25f, sb * 3.375f };

    // hashed sub-table base for q>=2: level 4q+lv -> [(q-2)*4 + lv] << 17
    const uint32_t l8base = ((uint32_t)((q >= 2 ? q - 2 : 0) * 4)) << 17;

    // ---- swizzled transpose-tile addressing (R2/R4-verified conflict-free)
    int wbase[4];
#pragma unroll
    for (int r = 0; r < 4; ++r)
        wbase[r] = (q * 4 + r) * 64 + m7 + ((mb ^ (r & 1)) << 3) + ((q & 1) << 5);
    const int rIdx0 = n16 * 64 + (( q      ^ m7) << 3);   // c=0
    const int rIdx1 = n16 * 64 + (((4 + q) ^ m7) << 3);   // c=1

    __syncthreads();   // wLds ready (only block-wide barrier)

    for (int g = blockIdx.x; g < nGroups; g += gridDim.x) {
        const int tile = g * 4 + wib;
        const int p = tile * 16 + n16;
        const float2 xy = ((const float2*)xin)[p];
        const float px = xy.x, py = xy.y;

        bf16x8 af;
#pragma unroll
        for (int lv = 0; lv < 4; ++lv) {
            const float posx = px * sc[lv], posy = py * sc[lv];
            const float fx = floorf(posx), fy = floorf(posy);
            const float frx = posx - fx,  fry = posy - fy;
            const uint32_t ix = (uint32_t)fx, iy = (uint32_t)fy;

            // dense geometry for this lv-slot (compile-time under unroll)
            const uint32_t Wl = (lv == 0) ? 17u  : (lv == 1) ? 25u
                              : (lv == 2) ? 37u  : 55u;
            const uint32_t Ol = (lv == 0) ? 0u   : (lv == 1) ? 289u
                              : (lv == 2) ? 914u : 2283u;
            const uint32_t Wg = (lv == 0) ? 82u    : (lv == 1) ? 123u
                              : (lv == 2) ? 184u   : 275u;
            const uint32_t Og = (lv == 0) ? 5308u  : (lv == 1) ? 12032u
                              : (lv == 2) ? 27161u : 61017u;

            uint32_t u00, u10, u01, u11;
            if (q < 2) {             // levels 0..7: dense tables (L1/L2)
                const uint32_t W = (q == 0) ? Wl : Wg;
                const uint32_t O = (q == 0) ? Ol : Og;
                const uint32_t a = O + iy * W + ix;
                u00 = dense[a];
                u10 = dense[a + 1];
                u01 = dense[a + W];
                u11 = dense[a + W + 1];
            } else {                 // levels 8..15: hashed fp8 (L2-resident)
                const uint32_t hy0 = iy * PRIME, hy1 = hy0 + PRIME;
                const uint32_t i00 = ( ix       ^ hy0) & HMASK;
                const uint32_t i10 = ((ix + 1u) ^ hy0) & HMASK;
                const uint32_t i01 = ( ix       ^ hy1) & HMASK;
                const uint32_t i11 = ((ix + 1u) ^ hy1) & HMASK;
                const uint32_t base = l8base + ((uint32_t)lv << 17);
                u00 = tab8[base + i00];
                u10 = tab8[base + i10];
                u01 = tab8[base + i01];
                u11 = tab8[base + i11];
            }

            const float2 e00 = unpack8w<false>(u00);
            const float2 e10 = unpack8w<false>(u10);
            const float2 e01 = unpack8w<false>(u01);
            const float2 e11 = unpack8w<false>(u11);
            const float wx1 = frx, wx0 = 1.0f - frx, wy1 = fry, wy0 = 1.0f - fry;
            const float w00 = wx0 * wy0, w10 = wx1 * wy0, w01 = wx0 * wy1, w11 = wx1 * wy1;
            // bilerp in the scaled (x2^13) domain; Bw0 un-scales.
            const float f0 = w00 * e00.x + w10 * e10.x + w01 * e01.x + w11 * e11.x;
            const float f1 = w00 * e00.y + w10 * e10.y + w01 * e01.y + w11 * e11.y;
            af[2 * lv]     = (bf16_t)f0;
            af[2 * lv + 1] = (bf16_t)f1;
        }

        // ---- layer 0: per-t {read Bw0[t] frag, MFMA, relu, transpose-write}
#pragma unroll
        for (int t = 0; t < 4; ++t) {
            const bf16x8 bw = *(const bf16x8*)&wLds[(t * 64 + lane) * 8];
            f32x4 cc = { bv0[t], bv0[t], bv0[t], bv0[t] };
            cc = __builtin_amdgcn_mfma_f32_16x16x32_bf16(af, bw, cc, 0, 0, 0);
#pragma unroll
            for (int r = 0; r < 4; ++r) {
                const int idx = ((t < 2) ? wbase[r] : (wbase[r] ^ 32))
                              + ((((t & 1) ^ ((r >> 1) & 1))) << 4);
                myLds[idx] = (bf16_t)fmaxf(cc[r], 0.0f);
            }
        }
        bf16x8 A1[2];
        A1[0] = *(const bf16x8*)&myLds[rIdx0];
        A1[1] = *(const bf16x8*)&myLds[rIdx1];

        // ---- layer 1: per-t {read 2 Bw1 frags, 2 MFMAs, relu, write}
#pragma unroll
        for (int t = 0; t < 4; ++t) {
            const bf16x8 bwa = *(const bf16x8*)&wLds[((4 + t) * 64 + lane) * 8];
            const bf16x8 bwb = *(const bf16x8*)&wLds[((8 + t) * 64 + lane) * 8];
            f32x4 cc = { bv1[t], bv1[t], bv1[t], bv1[t] };
            cc = __builtin_amdgcn_mfma_f32_16x16x32_bf16(A1[0], bwa, cc, 0, 0, 0);
            cc = __builtin_amdgcn_mfma_f32_16x16x32_bf16(A1[1], bwb, cc, 0, 0, 0);
#pragma unroll
            for (int r = 0; r < 4; ++r) {
                const int idx = ((t < 2) ? wbase[r] : (wbase[r] ^ 32))
                              + ((((t & 1) ^ ((r >> 1) & 1))) << 4);
                myLds[idx] = (bf16_t)fmaxf(cc[r], 0.0f);
            }
        }
        bf16x8 A2[2];
        A2[0] = *(const bf16x8*)&myLds[rIdx0];
        A2[1] = *(const bf16x8*)&myLds[rIdx1];

        // ---- layer 2: [16x64] @ [64x3 padded to 16] + b2 (no relu) ----
        f32x4 co = { bv2, bv2, bv2, bv2 };
        co = __builtin_amdgcn_mfma_f32_16x16x32_bf16(A2[0], Bw2[0], co, 0, 0, 0);
        co = __builtin_amdgcn_mfma_f32_16x16x32_bf16(A2[1], Bw2[1], co, 0, 0, 0);

        if (n16 < 3) {
#pragma unroll
            for (int r = 0; r < 4; ++r)
                out[(size_t)(tile * 16 + q * 4 + r) * 3 + n16] = co[r];
        }
    }
}

// ---- fallback (known-good): direct fp32 gather, used only if ws too small
__global__ __launch_bounds__(256)
void fused_hash_mlp_fp32(const float* __restrict__ xin,
                         const float* __restrict__ enc,
                         const float* __restrict__ w0, const float* __restrict__ b0,
                         const float* __restrict__ w1, const float* __restrict__ b1,
                         const float* __restrict__ w2, const float* __restrict__ b2,
                         float* __restrict__ out,
                         int nGroups)
{
    __shared__ __align__(16) bf16_t lds[4 * 16 * 80];
    const int tid  = threadIdx.x;
    const int wib  = tid >> 6;
    const int lane = tid & 63;
    const int q    = lane >> 4;
    const int n16  = lane & 15;
    bf16_t* myLds = &lds[wib * (16 * 80)];

    bf16x8 Bw0[4], Bw1[2][4], Bw2[2];
#pragma unroll
    for (int t = 0; t < 4; ++t)
#pragma unroll
        for (int j = 0; j < 8; ++j)
            Bw0[t][j] = (bf16_t)w0[(q * 8 + j) * 64 + t * 16 + n16];
#pragma unroll
    for (int c = 0; c < 2; ++c)
#pragma unroll
        for (int t = 0; t < 4; ++t)
#pragma unroll
            for (int j = 0; j < 8; ++j)
                Bw1[c][t][j] = (bf16_t)w1[(c * 32 + q * 8 + j) * 64 + t * 16 + n16];
#pragma unroll
    for (int c = 0; c < 2; ++c)
#pragma unroll
        for (int j = 0; j < 8; ++j)
            Bw2[c][j] = (n16 < 3) ? (bf16_t)w2[(c * 32 + q * 8 + j) * 3 + n16]
                                  : (bf16_t)0.0f;

    float bv0[4], bv1[4];
#pragma unroll
    for (int t = 0; t < 4; ++t) { bv0[t] = b0[t * 16 + n16]; bv1[t] = b1[t * 16 + n16]; }
    const float bv2 = (n16 < 3) ? b2[n16] : 0.0f;

    const float sb = 16.0f * ((q == 0) ? 1.0f : (q == 1) ? 5.0625f :
                              (q == 2) ? 25.62890625f : 129.746337890625f);
    const float sc[4] = { sb, sb * 1.5f, sb * 2.25f, sb * 3.375f };
    const char* encB = (const char*)enc;
    const uint32_t lvBase = (uint32_t)q * 32u;

    for (int g = blockIdx.x; g < nGroups; g += gridDim.x) {
        const int tile = g * 4 + wib;
        const int p = tile * 16 + n16;
        const float2 xy = ((const float2*)xin)[p];
        const float px = xy.x, py = xy.y;

        bf16x8 af;
#pragma unroll
        for (int lv = 0; lv < 4; ++lv) {
            const float posx = px * sc[lv], posy = py * sc[lv];
            const float fx = floorf(posx), fy = floorf(posy);
            const float frx = posx - fx,  fry = posy - fy;
            const uint32_t ix = (uint32_t)fx, iy = (uint32_t)fy;
            const uint32_t hy0 = iy * PRIME, hy1 = hy0 + PRIME;
            const uint32_t i00 = ( ix       ^ hy0) & HMASK;
            const uint32_t i10 = ((ix + 1u) ^ hy0) & HMASK;
            const uint32_t i01 = ( ix       ^ hy1) & HMASK;
            const uint32_t i11 = ((ix + 1u) ^ hy1) & HMASK;
            const uint32_t off = lvBase + (uint32_t)lv * 8u;
            const float2 e00 = *(const float2*)(encB + (i00 * 128u + off));
            const float2 e10 = *(const float2*)(encB + (i10 * 128u + off));
            const float2 e01 = *(const float2*)(encB + (i01 * 128u + off));
            const float2 e11 = *(const float2*)(encB + (i11 * 128u + off));
            const float wx1 = frx, wx0 = 1.0f - frx, wy1 = fry, wy0 = 1.0f - fry;
            const float w00 = wx0 * wy0, w10 = wx1 * wy0, w01 = wx0 * wy1, w11 = wx1 * wy1;
            af[2 * lv]     = (bf16_t)(w00 * e00.x + w10 * e10.x + w01 * e01.x + w11 * e11.x);
            af[2 * lv + 1] = (bf16_t)(w00 * e00.y + w10 * e10.y + w01 * e01.y + w11 * e11.y);
        }

        f32x4 c0[4];
#pragma unroll
        for (int t = 0; t < 4; ++t) {
            f32x4 cc = { bv0[t], bv0[t], bv0[t], bv0[t] };
            c0[t] = __builtin_amdgcn_mfma_f32_16x16x32_bf16(af, Bw0[t], cc, 0, 0, 0);
        }
        __syncthreads();
#pragma unroll
        for (int t = 0; t < 4; ++t)
#pragma unroll
            for (int r = 0; r < 4; ++r)
                myLds[(q * 4 + r) * 80 + t * 16 + n16] = (bf16_t)fmaxf(c0[t][r], 0.0f);
        __syncthreads();
        bf16x8 A1[2];
#pragma unroll
        for (int c = 0; c < 2; ++c)
            A1[c] = *(const bf16x8*)&myLds[n16 * 80 + c * 32 + q * 8];

        f32x4 c1[4];
#pragma unroll
        for (int t = 0; t < 4; ++t) {
            f32x4 cc = { bv1[t], bv1[t], bv1[t], bv1[t] };
            cc    = __builtin_amdgcn_mfma_f32_16x16x32_bf16(A1[0], Bw1[0][t], cc, 0, 0, 0);
            c1[t] = __builtin_amdgcn_mfma_f32_16x16x32_bf16(A1[1], Bw1[1][t], cc, 0, 0, 0);
        }
        __syncthreads();
#pragma unroll
        for (int t = 0; t < 4; ++t)
#pragma unroll
            for (int r = 0; r < 4; ++r)
                myLds[(q * 4 + r) * 80 + t * 16 + n16] = (bf16_t)fmaxf(c1[t][r], 0.0f);
        __syncthreads();
        bf16x8 A2[2];
#pragma unroll
        for (int c = 0; c < 2; ++c)
            A2[c] = *(const bf16x8*)&myLds[n16 * 80 + c * 32 + q * 8];

        f32x4 co = { bv2, bv2, bv2, bv2 };
        co = __builtin_amdgcn_mfma_f32_16x16x32_bf16(A2[0], Bw2[0], co, 0, 0, 0);
        co = __builtin_amdgcn_mfma_f32_16x16x32_bf16(A2[1], Bw2[1], co, 0, 0, 0);
        if (n16 < 3) {
#pragma unroll
            for (int r = 0; r < 4; ++r)
                out[(size_t)(tile * 16 + q * 4 + r) * 3 + n16] = co[r];
        }
    }
}

extern "C" void kernel_launch(void* const* d_in, const int* in_sizes, int n_in,
                              void* d_out, int out_size, void* d_ws, size_t ws_size,
                              hipStream_t stream) {
    const float* x  = (const float*)d_in[0];
    const float* en = (const float*)d_in[1];
    const float* w0 = (const float*)d_in[2];
    const float* b0 = (const float*)d_in[3];
    const float* w1 = (const float*)d_in[4];
    const float* b1 = (const float*)d_in[5];
    const float* w2 = (const float*)d_in[6];
    const float* b2 = (const float*)d_in[7];
    float* out = (float*)d_out;

    const int N = in_sizes[0] / 2;      // 2^20 points
    const int nTiles = N / 16;          // 65536
    const int nGroups = nTiles / 4;     // 16384 (4 waves/block)

    const size_t wsNeeded = ((size_t)TSIZE * 8 + NDALL) * 2;   // ~2.37 MB
    if (ws_size >= wsNeeded) {
        uint16_t* tab8  = (uint16_t*)d_ws;
        uint16_t* dense = tab8 + ((size_t)TSIZE * 8);
        const int preBlocks = 512 + (NDALL + 255) / 256;       // 1046
        prepass_all<<<preBlocks, 256, 0, stream>>>((const float2*)en, tab8, dense);
        int blocks = 2048;
        if (blocks > nGroups) blocks = nGroups;
        fused_hash_mlp<<<blocks, 256, 0, stream>>>(x, tab8, dense,
                                                   w0, b0, w1, b1, w2, b2, out, nGroups);
    } else {
        int blocks = 2048;
        if (blocks > nGroups) blocks = nGroups;
        fused_hash_mlp_fp32<<<blocks, 256, 0, stream>>>(x, en, w0, b0, w1, b1, w2, b2, out, nGroups);
    }
}

// Round 8
// 330.016 us; speedup vs baseline: 1.4953x; 1.4953x over previous
//
#include <hip/hip_runtime.h>
#include <stdint.h>

typedef __bf16 bf16_t;
typedef bf16_t bf16x8 __attribute__((ext_vector_type(8)));
typedef float  f32x4  __attribute__((ext_vector_type(4)));
typedef float  f32x2v __attribute__((ext_vector_type(2)));

static constexpr uint32_t PRIME = 2654435761u;
static constexpr uint32_t HMASK = (1u << 17) - 1u;   // HASHMAP_SIZE - 1
static constexpr uint32_t TSIZE = 1u << 17;

// dense mini-grid geometry, levels 0..7 (scale_l = 16*1.5^l, W = ceil(scale)+1)
static constexpr int NDALL  = 136642;   // 17^2+25^2+37^2+55^2+82^2+123^2+184^2+275^2

// features stored as fp8-e4m3 pairs, pre-scaled by 2^13 (|f|<=1e-4 -> +-0.82).
// un-scale 2^-13 is folded into the layer-0 weight fragments.
static constexpr float FSCALE = 8192.0f;        // 2^13
static constexpr float WSCALE = 1.0f / 8192.0f; // 2^-13

__device__ __forceinline__ uint32_t fbits(float f) {
    union { float f; uint32_t u; } v; v.f = f; return v.u;
}
__device__ __forceinline__ float asfloat(uint32_t u) {
    union { uint32_t u; float f; } v; v.u = u; return v.f;
}

// ---- fp8 pair encode/decode (OCP e4m3fn). HW path on gfx950, manual fallback.
__device__ __forceinline__ uint32_t enc8(float v) {   // manual e4m3fn RNE
    const uint32_t s = (fbits(v) >> 24) & 0x80u;
    float m = fabsf(v) * 0x1p-120f;                   // map e4m3 grid onto fp32 bits
    uint32_t u = fbits(m);
    u += 0x7FFFFu + ((u >> 20) & 1u);                 // RNE at bit 20
    return s | ((u >> 20) & 0x7fu);
}
__device__ __forceinline__ uint32_t pack8(float a, float b) {
#if __has_builtin(__builtin_amdgcn_cvt_pk_fp8_f32)
    return (uint32_t)__builtin_amdgcn_cvt_pk_fp8_f32(a, b, 0, false) & 0xffffu;
#else
    return enc8(a) | (enc8(b) << 8);
#endif
}
// unpack the low 16-bit fp8-pair of a dword (word-select must be an immediate)
template <bool HI>
__device__ __forceinline__ float2 unpack8w(uint32_t u) {
#if __has_builtin(__builtin_amdgcn_cvt_pk_f32_fp8)
    f32x2v r = __builtin_amdgcn_cvt_pk_f32_fp8((int)u, HI);
    return make_float2(r.x, r.y);
#else
    const uint32_t w = HI ? (u >> 16) : (u & 0xffffu);
    const float f0 = asfloat(((w & 0x80u) << 24) | ((w & 0x7fu) << 20)) * 0x1p120f;
    const float f1 = asfloat(((w & 0x8000u) << 16) | ((w & 0x7f00u) << 12)) * 0x1p120f;
    return make_float2(f0, f1);
#endif
}

// ---- single fused prepass (unchanged, HW-verified):
// blocks [0,512):  repack levels 8..15 of fp32 [T][L][F] -> fp8-pair ushorts,
//                  level-major [l-8][T] (2 MB), LDS-tiled transpose.
// blocks [512,..): dense mini-grids, levels 0..7 (267 KB, fp8-pair u16).
__global__ __launch_bounds__(256)
void prepass_all(const float2* __restrict__ src, uint16_t* __restrict__ tab8,
                 uint16_t* __restrict__ dense) {
    __shared__ uint16_t ldsT[8 * 257];      // [l8][t_local], +1 pad
    const int tid = threadIdx.x;
    if (blockIdx.x < 512) {
        const int t0 = blockIdx.x * 256;    // 512 blocks x 256 t-entries
#pragma unroll
        for (int k = 0; k < 8; ++k) {
            const int j = k * 256 + tid;    // (t_local, l8): l8 fastest
            const int tl = j >> 3, l8 = j & 7;
            const float2 f = src[((size_t)(t0 + tl) << 4) + 8 + l8];
            ldsT[l8 * 257 + tl] = (uint16_t)pack8(f.x * FSCALE, f.y * FSCALE);
        }
        __syncthreads();
#pragma unroll
        for (int k = 0; k < 8; ++k)
            tab8[((uint32_t)k << 17) + t0 + tid] = ldsT[k * 257 + tid];
    } else {
        const int i = (blockIdx.x - 512) * 256 + tid;
        if (i >= NDALL) return;
        int lvl, W, off;
        if      (i <   289) { lvl = 0; W =  17; off = 0;     }
        else if (i <   914) { lvl = 1; W =  25; off = 289;   }
        else if (i <  2283) { lvl = 2; W =  37; off = 914;   }
        else if (i <  5308) { lvl = 3; W =  55; off = 2283;  }
        else if (i < 12032) { lvl = 4; W =  82; off = 5308;  }
        else if (i < 27161) { lvl = 5; W = 123; off = 12032; }
        else if (i < 61017) { lvl = 6; W = 184; off = 27161; }
        else                { lvl = 7; W = 275; off = 61017; }
        const int li = i - off;
        const uint32_t iy = (uint32_t)(li / W), ix = (uint32_t)(li % W);
        const uint32_t h = (ix ^ (iy * PRIME)) & HMASK;
        const float2 f = src[h * 16 + lvl];
        dense[i] = (uint16_t)pack8(f.x * FSCALE, f.y * FSCALE);
    }
}

// OCCUPANCY ATTACK, take 2. R7 evidence: VGPR 32 (forced) -> occ 71% but
// 1.1 GB of spill traffic -> 420us. R4: VGPR 84 -> occ 29%, 130us. Target:
// natural VGPR <= 64, ZERO spills -> 8 waves/SIMD bracket (m69).
// Changes vs R7: (a) launch bound relaxed (256,8)->(256,4) so the allocator
// is not forced under its natural need (~55-60 by hand count); (b) ALL
// weight fragments incl. Bw2 now in LDS (14 slots, 14.3 KB) -> persistent
// register state is just biases+scales+addressing (~20 VGPR).
__global__ __launch_bounds__(256, 4)
void fused_hash_mlp(const float* __restrict__ xin,
                    const uint16_t* __restrict__ tab8,   // hashed lv8..15, fp8
                    const uint16_t* __restrict__ dense,  // dense lv0..7, fp8
                    const float* __restrict__ w0, const float* __restrict__ b0,
                    const float* __restrict__ w1, const float* __restrict__ b1,
                    const float* __restrict__ w2, const float* __restrict__ b2,
                    float* __restrict__ out,
                    int nGroups)
{
    __shared__ __align__(16) bf16_t lds[4 * 16 * 64];     // 8192 B transpose tiles
    __shared__ __align__(16) bf16_t wLds[14 * 64 * 8];    // 14336 B weight frags

    const int tid  = threadIdx.x;
    const int wib  = tid >> 6;      // 0..3
    const int lane = tid & 63;
    const int q    = lane >> 4;
    const int n16  = lane & 15;
    const int m7   = n16 & 7;
    const int mb   = n16 >> 3;

    bf16_t* myLds = &lds[wib * (16 * 64)];

    // ---- stage weight B-fragments into LDS (once; wave 0 writes).
    // slot 0..3  = Bw0[t]   (w0, absorbs 2^-13 un-scale)
    // slot 4..11 = Bw1[c*4+t]
    // slot 12,13 = Bw2[c]   (cols 3..15 zero-padded)
    {
        bf16x8 tmp;
#pragma unroll
        for (int t = 0; t < 4; ++t) {
#pragma unroll
            for (int j = 0; j < 8; ++j)
                tmp[j] = (bf16_t)(w0[(q * 8 + j) * 64 + t * 16 + n16] * WSCALE);
            if (wib == 0) *(bf16x8*)&wLds[(t * 64 + lane) * 8] = tmp;
        }
#pragma unroll
        for (int c = 0; c < 2; ++c)
#pragma unroll
            for (int t = 0; t < 4; ++t) {
#pragma unroll
                for (int j = 0; j < 8; ++j)
                    tmp[j] = (bf16_t)w1[(c * 32 + q * 8 + j) * 64 + t * 16 + n16];
                if (wib == 0) *(bf16x8*)&wLds[((4 + c * 4 + t) * 64 + lane) * 8] = tmp;
            }
#pragma unroll
        for (int c = 0; c < 2; ++c) {
#pragma unroll
            for (int j = 0; j < 8; ++j)
                tmp[j] = (n16 < 3) ? (bf16_t)w2[(c * 32 + q * 8 + j) * 3 + n16]
                                   : (bf16_t)0.0f;
            if (wib == 0) *(bf16x8*)&wLds[((12 + c) * 64 + lane) * 8] = tmp;
        }
    }

    // small persistent register state: biases only (9 VGPR)
    float bv0[4], bv1[4];
#pragma unroll
    for (int t = 0; t < 4; ++t) {
        bv0[t] = b0[t * 16 + n16];
        bv1[t] = b1[t * 16 + n16];
    }
    const float bv2 = (n16 < 3) ? b2[n16] : 0.0f;

    // scales for levels 4q..4q+3: 16*1.5^l = 3^l * 2^(4-l) is EXACT in fp32,
    // so pos/floor/hash bit-match the fp32 numpy reference.
    const float sb = 16.0f * ((q == 0) ? 1.0f :
                              (q == 1) ? 5.0625f :           // 1.5^4
                              (q == 2) ? 25.62890625f :      // 1.5^8
                                         129.746337890625f); // 1.5^12
    const float sc[4] = { sb, sb * 1.5f, sb * 2.25f, sb * 3.375f };

    // hashed sub-table base for q>=2: level 4q+lv -> [(q-2)*4 + lv] << 17
    const uint32_t l8base = ((uint32_t)((q >= 2 ? q - 2 : 0) * 4)) << 17;

    // ---- swizzled transpose-tile addressing (R2/R4-verified conflict-free)
    int wbase[4];
#pragma unroll
    for (int r = 0; r < 4; ++r)
        wbase[r] = (q * 4 + r) * 64 + m7 + ((mb ^ (r & 1)) << 3) + ((q & 1) << 5);
    const int rIdx0 = n16 * 64 + (( q      ^ m7) << 3);   // c=0
    const int rIdx1 = n16 * 64 + (((4 + q) ^ m7) << 3);   // c=1

    __syncthreads();   // wLds ready (only block-wide barrier)

    for (int g = blockIdx.x; g < nGroups; g += gridDim.x) {
        const int tile = g * 4 + wib;
        const int p = tile * 16 + n16;
        const float2 xy = ((const float2*)xin)[p];
        const float px = xy.x, py = xy.y;

        bf16x8 af;
#pragma unroll
        for (int lv = 0; lv < 4; ++lv) {
            const float posx = px * sc[lv], posy = py * sc[lv];
            const float fx = floorf(posx), fy = floorf(posy);
            const float frx = posx - fx,  fry = posy - fy;
            const uint32_t ix = (uint32_t)fx, iy = (uint32_t)fy;

            // dense geometry for this lv-slot (compile-time under unroll)
            const uint32_t Wl = (lv == 0) ? 17u  : (lv == 1) ? 25u
                              : (lv == 2) ? 37u  : 55u;
            const uint32_t Ol = (lv == 0) ? 0u   : (lv == 1) ? 289u
                              : (lv == 2) ? 914u : 2283u;
            const uint32_t Wg = (lv == 0) ? 82u    : (lv == 1) ? 123u
                              : (lv == 2) ? 184u   : 275u;
            const uint32_t Og = (lv == 0) ? 5308u  : (lv == 1) ? 12032u
                              : (lv == 2) ? 27161u : 61017u;

            uint32_t u00, u10, u01, u11;
            if (q < 2) {             // levels 0..7: dense tables (L1/L2)
                const uint32_t W = (q == 0) ? Wl : Wg;
                const uint32_t O = (q == 0) ? Ol : Og;
                const uint32_t a = O + iy * W + ix;
                u00 = dense[a];
                u10 = dense[a + 1];
                u01 = dense[a + W];
                u11 = dense[a + W + 1];
            } else {                 // levels 8..15: hashed fp8 (L2-resident)
                const uint32_t hy0 = iy * PRIME, hy1 = hy0 + PRIME;
                const uint32_t i00 = ( ix       ^ hy0) & HMASK;
                const uint32_t i10 = ((ix + 1u) ^ hy0) & HMASK;
                const uint32_t i01 = ( ix       ^ hy1) & HMASK;
                const uint32_t i11 = ((ix + 1u) ^ hy1) & HMASK;
                const uint32_t base = l8base + ((uint32_t)lv << 17);
                u00 = tab8[base + i00];
                u10 = tab8[base + i10];
                u01 = tab8[base + i01];
                u11 = tab8[base + i11];
            }

            const float2 e00 = unpack8w<false>(u00);
            const float2 e10 = unpack8w<false>(u10);
            const float2 e01 = unpack8w<false>(u01);
            const float2 e11 = unpack8w<false>(u11);
            const float wx1 = frx, wx0 = 1.0f - frx, wy1 = fry, wy0 = 1.0f - fry;
            const float w00 = wx0 * wy0, w10 = wx1 * wy0, w01 = wx0 * wy1, w11 = wx1 * wy1;
            // bilerp in the scaled (x2^13) domain; Bw0 un-scales.
            const float f0 = w00 * e00.x + w10 * e10.x + w01 * e01.x + w11 * e11.x;
            const float f1 = w00 * e00.y + w10 * e10.y + w01 * e01.y + w11 * e11.y;
            af[2 * lv]     = (bf16_t)f0;
            af[2 * lv + 1] = (bf16_t)f1;
        }

        // ---- layer 0: per-t {read Bw0[t] frag, MFMA, relu, transpose-write}
#pragma unroll
        for (int t = 0; t < 4; ++t) {
            const bf16x8 bw = *(const bf16x8*)&wLds[(t * 64 + lane) * 8];
            f32x4 cc = { bv0[t], bv0[t], bv0[t], bv0[t] };
            cc = __builtin_amdgcn_mfma_f32_16x16x32_bf16(af, bw, cc, 0, 0, 0);
#pragma unroll
            for (int r = 0; r < 4; ++r) {
                const int idx = ((t < 2) ? wbase[r] : (wbase[r] ^ 32))
                              + ((((t & 1) ^ ((r >> 1) & 1))) << 4);
                myLds[idx] = (bf16_t)fmaxf(cc[r], 0.0f);
            }
        }
        bf16x8 A1[2];
        A1[0] = *(const bf16x8*)&myLds[rIdx0];
        A1[1] = *(const bf16x8*)&myLds[rIdx1];

        // ---- layer 1: per-t {read 2 Bw1 frags, 2 MFMAs, relu, write}
#pragma unroll
        for (int t = 0; t < 4; ++t) {
            const bf16x8 bwa = *(const bf16x8*)&wLds[((4 + t) * 64 + lane) * 8];
            const bf16x8 bwb = *(const bf16x8*)&wLds[((8 + t) * 64 + lane) * 8];
            f32x4 cc = { bv1[t], bv1[t], bv1[t], bv1[t] };
            cc = __builtin_amdgcn_mfma_f32_16x16x32_bf16(A1[0], bwa, cc, 0, 0, 0);
            cc = __builtin_amdgcn_mfma_f32_16x16x32_bf16(A1[1], bwb, cc, 0, 0, 0);
#pragma unroll
            for (int r = 0; r < 4; ++r) {
                const int idx = ((t < 2) ? wbase[r] : (wbase[r] ^ 32))
                              + ((((t & 1) ^ ((r >> 1) & 1))) << 4);
                myLds[idx] = (bf16_t)fmaxf(cc[r], 0.0f);
            }
        }
        bf16x8 A2[2];
        A2[0] = *(const bf16x8*)&myLds[rIdx0];
        A2[1] = *(const bf16x8*)&myLds[rIdx1];

        // ---- layer 2: [16x64] @ [64x3 padded to 16] + b2 (no relu) ----
        {
            const bf16x8 bw2a = *(const bf16x8*)&wLds[(12 * 64 + lane) * 8];
            const bf16x8 bw2b = *(const bf16x8*)&wLds[(13 * 64 + lane) * 8];
            f32x4 co = { bv2, bv2, bv2, bv2 };
            co = __builtin_amdgcn_mfma_f32_16x16x32_bf16(A2[0], bw2a, co, 0, 0, 0);
            co = __builtin_amdgcn_mfma_f32_16x16x32_bf16(A2[1], bw2b, co, 0, 0, 0);

            if (n16 < 3) {
#pragma unroll
                for (int r = 0; r < 4; ++r)
                    out[(size_t)(tile * 16 + q * 4 + r) * 3 + n16] = co[r];
            }
        }
    }
}

// ---- fallback (known-good): direct fp32 gather, used only if ws too small
__global__ __launch_bounds__(256)
void fused_hash_mlp_fp32(const float* __restrict__ xin,
                         const float* __restrict__ enc,
                         const float* __restrict__ w0, const float* __restrict__ b0,
                         const float* __restrict__ w1, const float* __restrict__ b1,
                         const float* __restrict__ w2, const float* __restrict__ b2,
                         float* __restrict__ out,
                         int nGroups)
{
    __shared__ __align__(16) bf16_t lds[4 * 16 * 80];
    const int tid  = threadIdx.x;
    const int wib  = tid >> 6;
    const int lane = tid & 63;
    const int q    = lane >> 4;
    const int n16  = lane & 15;
    bf16_t* myLds = &lds[wib * (16 * 80)];

    bf16x8 Bw0[4], Bw1[2][4], Bw2[2];
#pragma unroll
    for (int t = 0; t < 4; ++t)
#pragma unroll
        for (int j = 0; j < 8; ++j)
            Bw0[t][j] = (bf16_t)w0[(q * 8 + j) * 64 + t * 16 + n16];
#pragma unroll
    for (int c = 0; c < 2; ++c)
#pragma unroll
        for (int t = 0; t < 4; ++t)
#pragma unroll
            for (int j = 0; j < 8; ++j)
                Bw1[c][t][j] = (bf16_t)w1[(c * 32 + q * 8 + j) * 64 + t * 16 + n16];
#pragma unroll
    for (int c = 0; c < 2; ++c)
#pragma unroll
        for (int j = 0; j < 8; ++j)
            Bw2[c][j] = (n16 < 3) ? (bf16_t)w2[(c * 32 + q * 8 + j) * 3 + n16]
                                  : (bf16_t)0.0f;

    float bv0[4], bv1[4];
#pragma unroll
    for (int t = 0; t < 4; ++t) { bv0[t] = b0[t * 16 + n16]; bv1[t] = b1[t * 16 + n16]; }
    const float bv2 = (n16 < 3) ? b2[n16] : 0.0f;

    const float sb = 16.0f * ((q == 0) ? 1.0f : (q == 1) ? 5.0625f :
                              (q == 2) ? 25.62890625f : 129.746337890625f);
    const float sc[4] = { sb, sb * 1.5f, sb * 2.25f, sb * 3.375f };
    const char* encB = (const char*)enc;
    const uint32_t lvBase = (uint32_t)q * 32u;

    for (int g = blockIdx.x; g < nGroups; g += gridDim.x) {
        const int tile = g * 4 + wib;
        const int p = tile * 16 + n16;
        const float2 xy = ((const float2*)xin)[p];
        const float px = xy.x, py = xy.y;

        bf16x8 af;
#pragma unroll
        for (int lv = 0; lv < 4; ++lv) {
            const float posx = px * sc[lv], posy = py * sc[lv];
            const float fx = floorf(posx), fy = floorf(posy);
            const float frx = posx - fx,  fry = posy - fy;
            const uint32_t ix = (uint32_t)fx, iy = (uint32_t)fy;
            const uint32_t hy0 = iy * PRIME, hy1 = hy0 + PRIME;
            const uint32_t i00 = ( ix       ^ hy0) & HMASK;
            const uint32_t i10 = ((ix + 1u) ^ hy0) & HMASK;
            const uint32_t i01 = ( ix       ^ hy1) & HMASK;
            const uint32_t i11 = ((ix + 1u) ^ hy1) & HMASK;
            const uint32_t off = lvBase + (uint32_t)lv * 8u;
            const float2 e00 = *(const float2*)(encB + (i00 * 128u + off));
            const float2 e10 = *(const float2*)(encB + (i10 * 128u + off));
            const float2 e01 = *(const float2*)(encB + (i01 * 128u + off));
            const float2 e11 = *(const float2*)(encB + (i11 * 128u + off));
            const float wx1 = frx, wx0 = 1.0f - frx, wy1 = fry, wy0 = 1.0f - fry;
            const float w00 = wx0 * wy0, w10 = wx1 * wy0, w01 = wx0 * wy1, w11 = wx1 * wy1;
            af[2 * lv]     = (bf16_t)(w00 * e00.x + w10 * e10.x + w01 * e01.x + w11 * e11.x);
            af[2 * lv + 1] = (bf16_t)(w00 * e00.y + w10 * e10.y + w01 * e01.y + w11 * e11.y);
        }

        f32x4 c0[4];
#pragma unroll
        for (int t = 0; t < 4; ++t) {
            f32x4 cc = { bv0[t], bv0[t], bv0[t], bv0[t] };
            c0[t] = __builtin_amdgcn_mfma_f32_16x16x32_bf16(af, Bw0[t], cc, 0, 0, 0);
        }
        __syncthreads();
#pragma unroll
        for (int t = 0; t < 4; ++t)
#pragma unroll
            for (int r = 0; r < 4; ++r)
                myLds[(q * 4 + r) * 80 + t * 16 + n16] = (bf16_t)fmaxf(c0[t][r], 0.0f);
        __syncthreads();
        bf16x8 A1[2];
#pragma unroll
        for (int c = 0; c < 2; ++c)
            A1[c] = *(const bf16x8*)&myLds[n16 * 80 + c * 32 + q * 8];

        f32x4 c1[4];
#pragma unroll
        for (int t = 0; t < 4; ++t) {
            f32x4 cc = { bv1[t], bv1[t], bv1[t], bv1[t] };
            cc    = __builtin_amdgcn_mfma_f32_16x16x32_bf16(A1[0], Bw1[0][t], cc, 0, 0, 0);
            c1[t] = __builtin_amdgcn_mfma_f32_16x16x32_bf16(A1[1], Bw1[1][t], cc, 0, 0, 0);
        }
        __syncthreads();
#pragma unroll
        for (int t = 0; t < 4; ++t)
#pragma unroll
            for (int r = 0; r < 4; ++r)
                myLds[(q * 4 + r) * 80 + t * 16 + n16] = (bf16_t)fmaxf(c1[t][r], 0.0f);
        __syncthreads();
        bf16x8 A2[2];
#pragma unroll
        for (int c = 0; c < 2; ++c)
            A2[c] = *(const bf16x8*)&myLds[n16 * 80 + c * 32 + q * 8];

        f32x4 co = { bv2, bv2, bv2, bv2 };
        co = __builtin_amdgcn_mfma_f32_16x16x32_bf16(A2[0], Bw2[0], co, 0, 0, 0);
        co = __builtin_amdgcn_mfma_f32_16x16x32_bf16(A2[1], Bw2[1], co, 0, 0, 0);
        if (n16 < 3) {
#pragma unroll
            for (int r = 0; r < 4; ++r)
                out[(size_t)(tile * 16 + q * 4 + r) * 3 + n16] = co[r];
        }
    }
}

extern "C" void kernel_launch(void* const* d_in, const int* in_sizes, int n_in,
                              void* d_out, int out_size, void* d_ws, size_t ws_size,
                              hipStream_t stream) {
    const float* x  = (const float*)d_in[0];
    const float* en = (const float*)d_in[1];
    const float* w0 = (const float*)d_in[2];
    const float* b0 = (const float*)d_in[3];
    const float* w1 = (const float*)d_in[4];
    const float* b1 = (const float*)d_in[5];
    const float* w2 = (const float*)d_in[6];
    const float* b2 = (const float*)d_in[7];
    float* out = (float*)d_out;

    const int N = in_sizes[0] / 2;      // 2^20 points
    const int nTiles = N / 16;          // 65536
    const int nGroups = nTiles / 4;     // 16384 (4 waves/block)

    const size_t wsNeeded = ((size_t)TSIZE * 8 + NDALL) * 2;   // ~2.37 MB
    if (ws_size >= wsNeeded) {
        uint16_t* tab8  = (uint16_t*)d_ws;
        uint16_t* dense = tab8 + ((size_t)TSIZE * 8);
        const int preBlocks = 512 + (NDALL + 255) / 256;       // 1046
        prepass_all<<<preBlocks, 256, 0, stream>>>((const float2*)en, tab8, dense);
        int blocks = 2048;
        if (blocks > nGroups) blocks = nGroups;
        fused_hash_mlp<<<blocks, 256, 0, stream>>>(x, tab8, dense,
                                                   w0, b0, w1, b1, w2, b2, out, nGroups);
    } else {
        int blocks = 2048;
        if (blocks > nGroups) blocks = nGroups;
        fused_hash_mlp_fp32<<<blocks, 256, 0, stream>>>(x, en, w0, b0, w1, b1, w2, b2, out, nGroups);
    }
}

// Round 9
// 199.419 us; speedup vs baseline: 2.4746x; 1.6549x over previous
//
#include <hip/hip_runtime.h>
#include <stdint.h>

typedef __bf16 bf16_t;
typedef bf16_t bf16x8 __attribute__((ext_vector_type(8)));
typedef float  f32x4  __attribute__((ext_vector_type(4)));
typedef float  f32x2v __attribute__((ext_vector_type(2)));

static constexpr uint32_t PRIME = 2654435761u;
static constexpr uint32_t HMASK = (1u << 17) - 1u;   // HASHMAP_SIZE - 1
static constexpr uint32_t TSIZE = 1u << 17;

// dense mini-grid geometry, levels 0..7 (scale_l = 16*1.5^l, W = ceil(scale)+1)
static constexpr int NLDS   = 5308;     // levels 0..3 (17^2+25^2+37^2+55^2)
static constexpr int NDALL  = 136642;   // + levels 4..7 (82^2+123^2+184^2+275^2)

// features stored as fp8-e4m3 pairs, pre-scaled by 2^13 (|f|<=1e-4 -> +-0.82).
// un-scale 2^-13 is folded into the layer-0 weight fragments.
static constexpr float FSCALE = 8192.0f;        // 2^13
static constexpr float WSCALE = 1.0f / 8192.0f; // 2^-13

__device__ __forceinline__ uint32_t fbits(float f) {
    union { float f; uint32_t u; } v; v.f = f; return v.u;
}
__device__ __forceinline__ float asfloat(uint32_t u) {
    union { uint32_t u; float f; } v; v.u = u; return v.f;
}

// ---- fp8 pair encode/decode (OCP e4m3fn). HW path on gfx950, manual fallback.
__device__ __forceinline__ uint32_t enc8(float v) {   // manual e4m3fn RNE
    const uint32_t s = (fbits(v) >> 24) & 0x80u;
    float m = fabsf(v) * 0x1p-120f;                   // map e4m3 grid onto fp32 bits
    uint32_t u = fbits(m);
    u += 0x7FFFFu + ((u >> 20) & 1u);                 // RNE at bit 20
    return s | ((u >> 20) & 0x7fu);
}
__device__ __forceinline__ uint32_t pack8(float a, float b) {
#if __has_builtin(__builtin_amdgcn_cvt_pk_fp8_f32)
    return (uint32_t)__builtin_amdgcn_cvt_pk_fp8_f32(a, b, 0, false) & 0xffffu;
#else
    return enc8(a) | (enc8(b) << 8);
#endif
}
// unpack the low 16-bit fp8-pair of a dword (word-select must be an immediate)
template <bool HI>
__device__ __forceinline__ float2 unpack8w(uint32_t u) {
#if __has_builtin(__builtin_amdgcn_cvt_pk_f32_fp8)
    f32x2v r = __builtin_amdgcn_cvt_pk_f32_fp8((int)u, HI);
    return make_float2(r.x, r.y);
#else
    const uint32_t w = HI ? (u >> 16) : (u & 0xffffu);
    const float f0 = asfloat(((w & 0x80u) << 24) | ((w & 0x7fu) << 20)) * 0x1p120f;
    const float f1 = asfloat(((w & 0x8000u) << 16) | ((w & 0x7f00u) << 12)) * 0x1p120f;
    return make_float2(f0, f1);
#endif
}

// ---- single fused prepass (HW-verified):
// blocks [0,512):  repack levels 8..15 of fp32 [T][L][F] -> fp8-pair ushorts,
//                  level-major [l-8][T] (2 MB), LDS-tiled transpose.
// blocks [512,..): dense mini-grids, levels 0..7 (267 KB, fp8-pair u16).
__global__ __launch_bounds__(256)
void prepass_all(const float2* __restrict__ src, uint16_t* __restrict__ tab8,
                 uint16_t* __restrict__ dense) {
    __shared__ uint16_t ldsT[8 * 257];      // [l8][t_local], +1 pad
    const int tid = threadIdx.x;
    if (blockIdx.x < 512) {
        const int t0 = blockIdx.x * 256;    // 512 blocks x 256 t-entries
#pragma unroll
        for (int k = 0; k < 8; ++k) {
            const int j = k * 256 + tid;    // (t_local, l8): l8 fastest
            const int tl = j >> 3, l8 = j & 7;
            const float2 f = src[((size_t)(t0 + tl) << 4) + 8 + l8];
            ldsT[l8 * 257 + tl] = (uint16_t)pack8(f.x * FSCALE, f.y * FSCALE);
        }
        __syncthreads();
#pragma unroll
        for (int k = 0; k < 8; ++k)
            tab8[((uint32_t)k << 17) + t0 + tid] = ldsT[k * 257 + tid];
    } else {
        const int i = (blockIdx.x - 512) * 256 + tid;
        if (i >= NDALL) return;
        int lvl, W, off;
        if      (i <   289) { lvl = 0; W =  17; off = 0;     }
        else if (i <   914) { lvl = 1; W =  25; off = 289;   }
        else if (i <  2283) { lvl = 2; W =  37; off = 914;   }
        else if (i <  5308) { lvl = 3; W =  55; off = 2283;  }
        else if (i < 12032) { lvl = 4; W =  82; off = 5308;  }
        else if (i < 27161) { lvl = 5; W = 123; off = 12032; }
        else if (i < 61017) { lvl = 6; W = 184; off = 27161; }
        else                { lvl = 7; W = 275; off = 61017; }
        const int li = i - off;
        const uint32_t iy = (uint32_t)(li / W), ix = (uint32_t)(li % W);
        const uint32_t h = (ix ^ (iy * PRIME)) & HMASK;
        const float2 f = src[h * 16 + lvl];
        dense[i] = (uint16_t)pack8(f.x * FSCALE, f.y * FSCALE);
    }
}

// R4 STRUCTURE (best-known-good: 130us, VGPR 84, zero spill) + EXACTLY ONE
// change: 1-deep x prefetch. The x-load is a cold HBM streaming read
// (~900cy) at the HEAD of the per-iteration serial chain (addr math ->
// gathers -> bilerp -> MFMA all depend on it). Prefetching next iteration's
// xy into one float2 register removes it from the chain. This was never
// isolated on the R4 base (R3 bundled it with regressions).
// Everything else byte-identical to R4: ldsTab LDS cache lv0-3, global dense
// lv4-7, hashed lv8-15, XOR-swizzled conflict-free transpose tiles, weights
// in registers, no block barriers in the loop.
__global__ __launch_bounds__(256, 2)
void fused_hash_mlp(const float* __restrict__ xin,
                    const uint16_t* __restrict__ tab8,   // hashed lv8..15, fp8
                    const uint16_t* __restrict__ dense,  // dense lv0..7, fp8
                    const float* __restrict__ w0, const float* __restrict__ b0,
                    const float* __restrict__ w1, const float* __restrict__ b1,
                    const float* __restrict__ w2, const float* __restrict__ b2,
                    float* __restrict__ out,
                    int nGroups)
{
    __shared__ uint16_t ldsTab[NLDS];                    // 10616 B
    __shared__ __align__(16) bf16_t lds[4 * 16 * 64];    // 8192 B per-wave tiles

    const int tid  = threadIdx.x;
    const int wib  = tid >> 6;      // 0..3
    const int lane = tid & 63;
    const int q    = lane >> 4;
    const int n16  = lane & 15;
    const int m7   = n16 & 7;
    const int mb   = n16 >> 3;

    bf16_t* myLds = &lds[wib * (16 * 64)];

    // cooperative fill of the LDS dense cache (levels 0..3)
    for (int i = tid; i < NLDS; i += 256) ldsTab[i] = dense[i];

    // ---- weight B-fragments (fp32 -> bf16 once). Bw0 absorbs the 2^-13
    // feature un-scale (A carries feat*2^13).
    bf16x8 Bw0[4], Bw1[2][4], Bw2[2];
#pragma unroll
    for (int t = 0; t < 4; ++t)
#pragma unroll
        for (int j = 0; j < 8; ++j)
            Bw0[t][j] = (bf16_t)(w0[(q * 8 + j) * 64 + t * 16 + n16] * WSCALE);
#pragma unroll
    for (int c = 0; c < 2; ++c)
#pragma unroll
        for (int t = 0; t < 4; ++t)
#pragma unroll
            for (int j = 0; j < 8; ++j)
                Bw1[c][t][j] = (bf16_t)w1[(c * 32 + q * 8 + j) * 64 + t * 16 + n16];
#pragma unroll
    for (int c = 0; c < 2; ++c)
#pragma unroll
        for (int j = 0; j < 8; ++j)
            Bw2[c][j] = (n16 < 3) ? (bf16_t)w2[(c * 32 + q * 8 + j) * 3 + n16]
                                  : (bf16_t)0.0f;

    float bv0[4], bv1[4];
#pragma unroll
    for (int t = 0; t < 4; ++t) {
        bv0[t] = b0[t * 16 + n16];
        bv1[t] = b1[t * 16 + n16];
    }
    const float bv2 = (n16 < 3) ? b2[n16] : 0.0f;

    // scales for levels 4q..4q+3: 16*1.5^l = 3^l * 2^(4-l) is EXACT in fp32,
    // so pos/floor/hash bit-match the fp32 numpy reference.
    const float sb = 16.0f * ((q == 0) ? 1.0f :
                              (q == 1) ? 5.0625f :           // 1.5^4
                              (q == 2) ? 25.62890625f :      // 1.5^8
                                         129.746337890625f); // 1.5^12
    const float sc[4] = { sb, sb * 1.5f, sb * 2.25f, sb * 3.375f };

    // hashed sub-table base for q>=2: level 4q+lv -> [(q-2)*4 + lv] << 17
    const uint32_t l8base = ((uint32_t)((q >= 2 ? q - 2 : 0) * 4)) << 17;

    // ---- swizzled transpose-tile addressing (R2/R4-verified conflict-free)
    int wbase[4];
#pragma unroll
    for (int r = 0; r < 4; ++r)
        wbase[r] = (q * 4 + r) * 64 + m7 + ((mb ^ (r & 1)) << 3) + ((q & 1) << 5);
    const int rIdx0 = n16 * 64 + (( q      ^ m7) << 3);   // c=0
    const int rIdx1 = n16 * 64 + (((4 + q) ^ m7) << 3);   // c=1

    __syncthreads();   // ldsTab ready (only block-wide barrier)

    int g = blockIdx.x;
    if (g >= nGroups) return;

    // prologue: first x (HBM)
    float2 xy = ((const float2*)xin)[(g * 4 + wib) * 16 + n16];

    for (; g < nGroups; g += gridDim.x) {
        // 1-deep x prefetch: issue next iteration's x load NOW so its ~900cy
        // HBM latency overlaps this iteration's gathers + MFMA chain.
        const int gN = g + gridDim.x;
        const int gSafe = (gN < nGroups) ? gN : g;
        const float2 xyN = ((const float2*)xin)[(gSafe * 4 + wib) * 16 + n16];

        const int tile = g * 4 + wib;
        const float px = xy.x, py = xy.y;

        bf16x8 af;
#pragma unroll
        for (int lv = 0; lv < 4; ++lv) {
            const float posx = px * sc[lv], posy = py * sc[lv];
            const float fx = floorf(posx), fy = floorf(posy);
            const float frx = posx - fx,  fry = posy - fy;
            const uint32_t ix = (uint32_t)fx, iy = (uint32_t)fy;

            // dense geometry for this lv-slot (compile-time under unroll)
            const uint32_t Wl = (lv == 0) ? 17u  : (lv == 1) ? 25u
                              : (lv == 2) ? 37u  : 55u;
            const uint32_t Ol = (lv == 0) ? 0u   : (lv == 1) ? 289u
                              : (lv == 2) ? 914u : 2283u;
            const uint32_t Wg = (lv == 0) ? 82u    : (lv == 1) ? 123u
                              : (lv == 2) ? 184u   : 275u;
            const uint32_t Og = (lv == 0) ? 5308u  : (lv == 1) ? 12032u
                              : (lv == 2) ? 27161u : 61017u;

            uint32_t u00, u10, u01, u11;
            if (q == 0) {            // levels 0..3: LDS dense
                const uint32_t a = Ol + iy * Wl + ix;
                u00 = ldsTab[a];
                u10 = ldsTab[a + 1];
                u01 = ldsTab[a + Wl];
                u11 = ldsTab[a + Wl + 1];
            } else if (q == 1) {     // levels 4..7: global dense (L2-resident)
                const uint32_t a = Og + iy * Wg + ix;
                u00 = dense[a];
                u10 = dense[a + 1];
                u01 = dense[a + Wg];
                u11 = dense[a + Wg + 1];
            } else {                 // levels 8..15: hashed fp8 (L2-resident)
                const uint32_t hy0 = iy * PRIME, hy1 = hy0 + PRIME;
                const uint32_t i00 = ( ix       ^ hy0) & HMASK;
                const uint32_t i10 = ((ix + 1u) ^ hy0) & HMASK;
                const uint32_t i01 = ( ix       ^ hy1) & HMASK;
                const uint32_t i11 = ((ix + 1u) ^ hy1) & HMASK;
                const uint32_t base = l8base + ((uint32_t)lv << 17);
                u00 = tab8[base + i00];
                u10 = tab8[base + i10];
                u01 = tab8[base + i01];
                u11 = tab8[base + i11];
            }

            const float2 e00 = unpack8w<false>(u00);
            const float2 e10 = unpack8w<false>(u10);
            const float2 e01 = unpack8w<false>(u01);
            const float2 e11 = unpack8w<false>(u11);
            const float wx1 = frx, wx0 = 1.0f - frx, wy1 = fry, wy0 = 1.0f - fry;
            const float w00 = wx0 * wy0, w10 = wx1 * wy0, w01 = wx0 * wy1, w11 = wx1 * wy1;
            // bilerp in the scaled (x2^13) domain; Bw0 un-scales.
            const float f0 = w00 * e00.x + w10 * e10.x + w01 * e01.x + w11 * e11.x;
            const float f1 = w00 * e00.y + w10 * e10.y + w01 * e01.y + w11 * e11.y;
            af[2 * lv]     = (bf16_t)f0;
            af[2 * lv + 1] = (bf16_t)f1;
        }

        // ---- layer 0: [16x32] @ [32x64] + b0, relu ----
        f32x4 c0[4];
#pragma unroll
        for (int t = 0; t < 4; ++t) {
            f32x4 cc = { bv0[t], bv0[t], bv0[t], bv0[t] };
            c0[t] = __builtin_amdgcn_mfma_f32_16x16x32_bf16(af, Bw0[t], cc, 0, 0, 0);
        }

        // C-layout -> A-layout via per-wave private swizzled LDS tile
#pragma unroll
        for (int t = 0; t < 4; ++t)
#pragma unroll
            for (int r = 0; r < 4; ++r) {
                const int idx = ((t < 2) ? wbase[r] : (wbase[r] ^ 32))
                              + ((((t & 1) ^ ((r >> 1) & 1))) << 4);
                myLds[idx] = (bf16_t)fmaxf(c0[t][r], 0.0f);
            }
        bf16x8 A1[2];
        A1[0] = *(const bf16x8*)&myLds[rIdx0];
        A1[1] = *(const bf16x8*)&myLds[rIdx1];

        // ---- layer 1: [16x64] @ [64x64] + b1, relu ----
        f32x4 c1[4];
#pragma unroll
        for (int t = 0; t < 4; ++t) {
            f32x4 cc = { bv1[t], bv1[t], bv1[t], bv1[t] };
            cc    = __builtin_amdgcn_mfma_f32_16x16x32_bf16(A1[0], Bw1[0][t], cc, 0, 0, 0);
            c1[t] = __builtin_amdgcn_mfma_f32_16x16x32_bf16(A1[1], Bw1[1][t], cc, 0, 0, 0);
        }

#pragma unroll
        for (int t = 0; t < 4; ++t)
#pragma unroll
            for (int r = 0; r < 4; ++r) {
                const int idx = ((t < 2) ? wbase[r] : (wbase[r] ^ 32))
                              + ((((t & 1) ^ ((r >> 1) & 1))) << 4);
                myLds[idx] = (bf16_t)fmaxf(c1[t][r], 0.0f);
            }
        bf16x8 A2[2];
        A2[0] = *(const bf16x8*)&myLds[rIdx0];
        A2[1] = *(const bf16x8*)&myLds[rIdx1];

        // ---- layer 2: [16x64] @ [64x3 padded to 16] + b2 (no relu) ----
        f32x4 co = { bv2, bv2, bv2, bv2 };
        co = __builtin_amdgcn_mfma_f32_16x16x32_bf16(A2[0], Bw2[0], co, 0, 0, 0);
        co = __builtin_amdgcn_mfma_f32_16x16x32_bf16(A2[1], Bw2[1], co, 0, 0, 0);

        if (n16 < 3) {
#pragma unroll
            for (int r = 0; r < 4; ++r)
                out[(size_t)(tile * 16 + q * 4 + r) * 3 + n16] = co[r];
        }

        xy = xyN;   // rotate the prefetched x
    }
}

// ---- fallback (known-good): direct fp32 gather, used only if ws too small
__global__ __launch_bounds__(256)
void fused_hash_mlp_fp32(const float* __restrict__ xin,
                         const float* __restrict__ enc,
                         const float* __restrict__ w0, const float* __restrict__ b0,
                         const float* __restrict__ w1, const float* __restrict__ b1,
                         const float* __restrict__ w2, const float* __restrict__ b2,
                         float* __restrict__ out,
                         int nGroups)
{
    __shared__ __align__(16) bf16_t lds[4 * 16 * 80];
    const int tid  = threadIdx.x;
    const int wib  = tid >> 6;
    const int lane = tid & 63;
    const int q    = lane >> 4;
    const int n16  = lane & 15;
    bf16_t* myLds = &lds[wib * (16 * 80)];

    bf16x8 Bw0[4], Bw1[2][4], Bw2[2];
#pragma unroll
    for (int t = 0; t < 4; ++t)
#pragma unroll
        for (int j = 0; j < 8; ++j)
            Bw0[t][j] = (bf16_t)w0[(q * 8 + j) * 64 + t * 16 + n16];
#pragma unroll
    for (int c = 0; c < 2; ++c)
#pragma unroll
        for (int t = 0; t < 4; ++t)
#pragma unroll
            for (int j = 0; j < 8; ++j)
                Bw1[c][t][j] = (bf16_t)w1[(c * 32 + q * 8 + j) * 64 + t * 16 + n16];
#pragma unroll
    for (int c = 0; c < 2; ++c)
#pragma unroll
        for (int j = 0; j < 8; ++j)
            Bw2[c][j] = (n16 < 3) ? (bf16_t)w2[(c * 32 + q * 8 + j) * 3 + n16]
                                  : (bf16_t)0.0f;

    float bv0[4], bv1[4];
#pragma unroll
    for (int t = 0; t < 4; ++t) { bv0[t] = b0[t * 16 + n16]; bv1[t] = b1[t * 16 + n16]; }
    const float bv2 = (n16 < 3) ? b2[n16] : 0.0f;

    const float sb = 16.0f * ((q == 0) ? 1.0f : (q == 1) ? 5.0625f :
                              (q == 2) ? 25.62890625f : 129.746337890625f);
    const float sc[4] = { sb, sb * 1.5f, sb * 2.25f, sb * 3.375f };
    const char* encB = (const char*)enc;
    const uint32_t lvBase = (uint32_t)q * 32u;

    for (int g = blockIdx.x; g < nGroups; g += gridDim.x) {
        const int tile = g * 4 + wib;
        const int p = tile * 16 + n16;
        const float2 xy = ((const float2*)xin)[p];
        const float px = xy.x, py = xy.y;

        bf16x8 af;
#pragma unroll
        for (int lv = 0; lv < 4; ++lv) {
            const float posx = px * sc[lv], posy = py * sc[lv];
            const float fx = floorf(posx), fy = floorf(posy);
            const float frx = posx - fx,  fry = posy - fy;
            const uint32_t ix = (uint32_t)fx, iy = (uint32_t)fy;
            const uint32_t hy0 = iy * PRIME, hy1 = hy0 + PRIME;
            const uint32_t i00 = ( ix       ^ hy0) & HMASK;
            const uint32_t i10 = ((ix + 1u) ^ hy0) & HMASK;
            const uint32_t i01 = ( ix       ^ hy1) & HMASK;
            const uint32_t i11 = ((ix + 1u) ^ hy1) & HMASK;
            const uint32_t off = lvBase + (uint32_t)lv * 8u;
            const float2 e00 = *(const float2*)(encB + (i00 * 128u + off));
            const float2 e10 = *(const float2*)(encB + (i10 * 128u + off));
            const float2 e01 = *(const float2*)(encB + (i01 * 128u + off));
            const float2 e11 = *(const float2*)(encB + (i11 * 128u + off));
            const float wx1 = frx, wx0 = 1.0f - frx, wy1 = fry, wy0 = 1.0f - fry;
            const float w00 = wx0 * wy0, w10 = wx1 * wy0, w01 = wx0 * wy1, w11 = wx1 * wy1;
            af[2 * lv]     = (bf16_t)(w00 * e00.x + w10 * e10.x + w01 * e01.x + w11 * e11.x);
            af[2 * lv + 1] = (bf16_t)(w00 * e00.y + w10 * e10.y + w01 * e01.y + w11 * e11.y);
        }

        f32x4 c0[4];
#pragma unroll
        for (int t = 0; t < 4; ++t) {
            f32x4 cc = { bv0[t], bv0[t], bv0[t], bv0[t] };
            c0[t] = __builtin_amdgcn_mfma_f32_16x16x32_bf16(af, Bw0[t], cc, 0, 0, 0);
        }
        __syncthreads();
#pragma unroll
        for (int t = 0; t < 4; ++t)
#pragma unroll
            for (int r = 0; r < 4; ++r)
                myLds[(q * 4 + r) * 80 + t * 16 + n16] = (bf16_t)fmaxf(c0[t][r], 0.0f);
        __syncthreads();
        bf16x8 A1[2];
#pragma unroll
        for (int c = 0; c < 2; ++c)
            A1[c] = *(const bf16x8*)&myLds[n16 * 80 + c * 32 + q * 8];

        f32x4 c1[4];
#pragma unroll
        for (int t = 0; t < 4; ++t) {
            f32x4 cc = { bv1[t], bv1[t], bv1[t], bv1[t] };
            cc    = __builtin_amdgcn_mfma_f32_16x16x32_bf16(A1[0], Bw1[0][t], cc, 0, 0, 0);
            c1[t] = __builtin_amdgcn_mfma_f32_16x16x32_bf16(A1[1], Bw1[1][t], cc, 0, 0, 0);
        }
        __syncthreads();
#pragma unroll
        for (int t = 0; t < 4; ++t)
#pragma unroll
            for (int r = 0; r < 4; ++r)
                myLds[(q * 4 + r) * 80 + t * 16 + n16] = (bf16_t)fmaxf(c1[t][r], 0.0f);
        __syncthreads();
        bf16x8 A2[2];
#pragma unroll
        for (int c = 0; c < 2; ++c)
            A2[c] = *(const bf16x8*)&myLds[n16 * 80 + c * 32 + q * 8];

        f32x4 co = { bv2, bv2, bv2, bv2 };
        co = __builtin_amdgcn_mfma_f32_16x16x32_bf16(A2[0], Bw2[0], co, 0, 0, 0);
        co = __builtin_amdgcn_mfma_f32_16x16x32_bf16(A2[1], Bw2[1], co, 0, 0, 0);
        if (n16 < 3) {
#pragma unroll
            for (int r = 0; r < 4; ++r)
                out[(size_t)(tile * 16 + q * 4 + r) * 3 + n16] = co[r];
        }
    }
}

extern "C" void kernel_launch(void* const* d_in, const int* in_sizes, int n_in,
                              void* d_out, int out_size, void* d_ws, size_t ws_size,
                              hipStream_t stream) {
    const float* x  = (const float*)d_in[0];
    const float* en = (const float*)d_in[1];
    const float* w0 = (const float*)d_in[2];
    const float* b0 = (const float*)d_in[3];
    const float* w1 = (const float*)d_in[4];
    const float* b1 = (const float*)d_in[5];
    const float* w2 = (const float*)d_in[6];
    const float* b2 = (const float*)d_in[7];
    float* out = (float*)d_out;

    const int N = in_sizes[0] / 2;      // 2^20 points
    const int nTiles = N / 16;          // 65536
    const int nGroups = nTiles / 4;     // 16384 (4 waves/block)

    const size_t wsNeeded = ((size_t)TSIZE * 8 + NDALL) * 2;   // ~2.37 MB
    if (ws_size >= wsNeeded) {
        uint16_t* tab8  = (uint16_t*)d_ws;
        uint16_t* dense = tab8 + ((size_t)TSIZE * 8);
        const int preBlocks = 512 + (NDALL + 255) / 256;       // 1046
        prepass_all<<<preBlocks, 256, 0, stream>>>((const float2*)en, tab8, dense);
        int blocks = 2048;
        if (blocks > nGroups) blocks = nGroups;
        fused_hash_mlp<<<blocks, 256, 0, stream>>>(x, tab8, dense,
                                                   w0, b0, w1, b1, w2, b2, out, nGroups);
    } else {
        int blocks = 2048;
        if (blocks > nGroups) blocks = nGroups;
        fused_hash_mlp_fp32<<<blocks, 256, 0, stream>>>(x, en, w0, b0, w1, b1, w2, b2, out, nGroups);
    }
}